// Round 1
// baseline (908.396 us; speedup 1.0000x reference)
//
#include <hip/hip_runtime.h>
#include <cstddef>

#define BATCH 4
#define SEQ   1024
#define DM    1024
#define NH    16
#define HD    64
#define D3    3072

// ---------------- GEMM: C[M,N] = A[M,K] @ W[K,N] + bias[N] ----------------
// 64x64 tile, BK=16, 256 threads, 4x4 per thread. fp32 vector ALU.
__global__ __launch_bounds__(256) void gemm_bias_kernel(
    const float* __restrict__ A, const float* __restrict__ W,
    const float* __restrict__ bias, float* __restrict__ C,
    int M, int N, int K)
{
  __shared__ float As[16][68];   // As[k][m], pad 68: 2-way conflicts only
  __shared__ float Ws[16][68];   // Ws[k][n]
  const int tid = threadIdx.x;
  const int tx = tid & 15, ty = tid >> 4;
  const int bx = blockIdx.x, by = blockIdx.y;
  const int ar = tid >> 2, ac = (tid & 3) << 2;  // A tile: 64 rows x 16 k
  const int wr = ty, wc = tx << 2;               // W tile: 16 k x 64 cols
  float acc[4][4] = {};
  for (int k0 = 0; k0 < K; k0 += 16) {
    float4 a = *(const float4*)(A + (size_t)(by*64 + ar)*K + k0 + ac);
    float4 w = *(const float4*)(W + (size_t)(k0 + wr)*N + bx*64 + wc);
    As[ac+0][ar] = a.x; As[ac+1][ar] = a.y; As[ac+2][ar] = a.z; As[ac+3][ar] = a.w;
    *(float4*)(&Ws[wr][wc]) = w;
    __syncthreads();
#pragma unroll
    for (int kk = 0; kk < 16; ++kk) {
      const float4 av = *(const float4*)(&As[kk][ty << 2]);
      const float4 wv = *(const float4*)(&Ws[kk][tx << 2]);
      const float aa[4] = {av.x, av.y, av.z, av.w};
      const float ww[4] = {wv.x, wv.y, wv.z, wv.w};
#pragma unroll
      for (int i = 0; i < 4; ++i)
#pragma unroll
        for (int j = 0; j < 4; ++j)
          acc[i][j] += aa[i] * ww[j];
    }
    __syncthreads();
  }
  const int row0 = by*64 + (ty << 2);
  const int col0 = bx*64 + (tx << 2);
  const float4 bv = *(const float4*)(bias + col0);
  const float bb[4] = {bv.x, bv.y, bv.z, bv.w};
#pragma unroll
  for (int i = 0; i < 4; ++i) {
    float4 o;
    o.x = acc[i][0] + bb[0];
    o.y = acc[i][1] + bb[1];
    o.z = acc[i][2] + bb[2];
    o.w = acc[i][3] + bb[3];
    *(float4*)(C + (size_t)(row0 + i)*N + col0) = o;
  }
}

// ---------------- Flash-style attention, fp32 ----------------
// qkv layout: [B, S, 3072], head h occupies cols h*192 + {0:q, 64:k, 128:v}.
// Block: (b,h) x 64-row Q tile. K/V tiles of 64 share one LDS buffer.
// Thread (ty,tx): QK covers q rows 4ty+i, k cols tx+16j (avoids 8-way LDS
// conflicts that 4tx+j row-spacing would cause); PV covers q rows 4ty+i,
// hd cols 4tx+j. P transits LDS. Scale 1/8 folded into Q load.
__global__ __launch_bounds__(256) void attn_kernel(
    const float* __restrict__ qkv, const int* __restrict__ mask,
    float* __restrict__ vals)
{
  __shared__ float Qs[64][68];
  __shared__ float KVs[64][68];
  __shared__ float Ps[64][68];
  const int tid = threadIdx.x;
  const int tx = tid & 15, ty = tid >> 4;
  const int b = blockIdx.y >> 4, h = blockIdx.y & 15;
  const int q0 = blockIdx.x << 6;
  const float* hb = qkv + (size_t)b * SEQ * D3 + h * (3 * HD);
  const int lr = tid >> 4;          // 0..15
  const int lc = (tid & 15) << 2;   // 0..60
#pragma unroll
  for (int it = 0; it < 4; ++it) {
    const int r = it*16 + lr;
    float4 v = *(const float4*)(hb + (size_t)(q0 + r)*D3 + lc);
    v.x *= 0.125f; v.y *= 0.125f; v.z *= 0.125f; v.w *= 0.125f;
    *(float4*)(&Qs[r][lc]) = v;
  }
  float m_[4], l_[4], o_[4][4];
#pragma unroll
  for (int i = 0; i < 4; ++i) {
    m_[i] = -1e30f; l_[i] = 0.f;
#pragma unroll
    for (int j = 0; j < 4; ++j) o_[i][j] = 0.f;
  }
  for (int kt = 0; kt < 16; ++kt) {
    const int k0 = kt << 6;
    // stage K tile
#pragma unroll
    for (int it = 0; it < 4; ++it) {
      const int r = it*16 + lr;
      *(float4*)(&KVs[r][lc]) = *(const float4*)(hb + (size_t)(k0 + r)*D3 + HD + lc);
    }
    __syncthreads();
    // S = (Q/8) K^T
    float s[4][4] = {};
#pragma unroll
    for (int d4 = 0; d4 < 16; ++d4) {
      float4 q4[4], k4[4];
#pragma unroll
      for (int i = 0; i < 4; ++i) q4[i] = *(const float4*)(&Qs[(ty<<2) + i][d4<<2]);
#pragma unroll
      for (int j = 0; j < 4; ++j) k4[j] = *(const float4*)(&KVs[tx + (j<<4)][d4<<2]);
#pragma unroll
      for (int i = 0; i < 4; ++i)
#pragma unroll
        for (int j = 0; j < 4; ++j)
          s[i][j] += q4[i].x*k4[j].x + q4[i].y*k4[j].y + q4[i].z*k4[j].z + q4[i].w*k4[j].w;
    }
    // mask + online softmax + stage P
#pragma unroll
    for (int i = 0; i < 4; ++i) {
      const int* mrow = mask + (size_t)b*SEQ*SEQ + (size_t)(q0 + (ty<<2) + i)*SEQ + k0;
#pragma unroll
      for (int j = 0; j < 4; ++j)
        if (mrow[tx + (j<<4)] == 0) s[i][j] = -1e20f;
      float rmax = fmaxf(fmaxf(s[i][0], s[i][1]), fmaxf(s[i][2], s[i][3]));
      rmax = fmaxf(rmax, __shfl_xor(rmax, 1));
      rmax = fmaxf(rmax, __shfl_xor(rmax, 2));
      rmax = fmaxf(rmax, __shfl_xor(rmax, 4));
      rmax = fmaxf(rmax, __shfl_xor(rmax, 8));
      const float mnew = fmaxf(m_[i], rmax);
      const float alpha = __expf(m_[i] - mnew);
      float p[4], rsum = 0.f;
#pragma unroll
      for (int j = 0; j < 4; ++j) { p[j] = __expf(s[i][j] - mnew); rsum += p[j]; }
      rsum += __shfl_xor(rsum, 1);
      rsum += __shfl_xor(rsum, 2);
      rsum += __shfl_xor(rsum, 4);
      rsum += __shfl_xor(rsum, 8);
      l_[i] = l_[i]*alpha + rsum;
      m_[i] = mnew;
#pragma unroll
      for (int j = 0; j < 4; ++j) o_[i][j] *= alpha;
#pragma unroll
      for (int j = 0; j < 4; ++j) Ps[(ty<<2) + i][tx + (j<<4)] = p[j];
    }
    __syncthreads();
    // stage V tile (overwrites K)
#pragma unroll
    for (int it = 0; it < 4; ++it) {
      const int r = it*16 + lr;
      *(float4*)(&KVs[r][lc]) = *(const float4*)(hb + (size_t)(k0 + r)*D3 + 2*HD + lc);
    }
    __syncthreads();
    // O += P V
#pragma unroll
    for (int k4 = 0; k4 < 16; ++k4) {
      float4 p4[4], v4[4];
#pragma unroll
      for (int i = 0; i < 4; ++i) p4[i] = *(const float4*)(&Ps[(ty<<2) + i][k4<<2]);
#pragma unroll
      for (int kk = 0; kk < 4; ++kk) v4[kk] = *(const float4*)(&KVs[(k4<<2) + kk][tx<<2]);
      float pm[4][4], vm[4][4];
#pragma unroll
      for (int i = 0; i < 4; ++i) {
        pm[i][0] = p4[i].x; pm[i][1] = p4[i].y; pm[i][2] = p4[i].z; pm[i][3] = p4[i].w;
        vm[i][0] = v4[i].x; vm[i][1] = v4[i].y; vm[i][2] = v4[i].z; vm[i][3] = v4[i].w;
      }
#pragma unroll
      for (int kk = 0; kk < 4; ++kk)
#pragma unroll
        for (int i = 0; i < 4; ++i)
#pragma unroll
          for (int j = 0; j < 4; ++j)
            o_[i][j] += pm[i][kk] * vm[kk][j];
    }
    __syncthreads();
  }
  // normalize + write vals[b, q, h*64 + d]
#pragma unroll
  for (int i = 0; i < 4; ++i) {
    const float inv = 1.0f / l_[i];
    float4 o;
    o.x = o_[i][0]*inv; o.y = o_[i][1]*inv; o.z = o_[i][2]*inv; o.w = o_[i][3]*inv;
    *(float4*)(vals + (size_t)(b*SEQ + q0 + (ty<<2) + i)*DM + h*HD + (tx<<2)) = o;
  }
}

extern "C" void kernel_launch(void* const* d_in, const int* in_sizes, int n_in,
                              void* d_out, int out_size, void* d_ws, size_t ws_size,
                              hipStream_t stream) {
  const float* x    = (const float*)d_in[0];
  const int*   mask = (const int*)  d_in[1];
  const float* Wqkv = (const float*)d_in[2];
  const float* bqkv = (const float*)d_in[3];
  const float* Wo   = (const float*)d_in[4];
  const float* bo   = (const float*)d_in[5];
  float* out  = (float*)d_out;
  float* qkv  = (float*)d_ws;                       // 4*1024*3072 floats (48 MB)
  float* vals = qkv + (size_t)BATCH*SEQ*D3;         // 4*1024*1024 floats (16 MB)

  // 1) qkv = x @ Wqkv + bqkv   [4096 x 3072]
  gemm_bias_kernel<<<dim3(D3/64, (BATCH*SEQ)/64), dim3(256), 0, stream>>>(
      x, Wqkv, bqkv, qkv, BATCH*SEQ, D3, DM);
  // 2) flash attention -> vals [B,S,D] (already in x-layout)
  attn_kernel<<<dim3(SEQ/64, BATCH*NH), dim3(256), 0, stream>>>(qkv, mask, vals);
  // 3) out = vals @ Wo + bo    [4096 x 1024]
  gemm_bias_kernel<<<dim3(DM/64, (BATCH*SEQ)/64), dim3(256), 0, stream>>>(
      vals, Wo, bo, out, BATCH*SEQ, DM, DM);
}

// Round 2
// 249.895 us; speedup vs baseline: 3.6351x; 3.6351x over previous
//
#include <hip/hip_runtime.h>
#include <cstddef>
#include <cstdint>

#define BATCH 4
#define SEQ   1024
#define DM    1024
#define NH    16
#define HD    64
#define D3    3072

typedef _Float16 f16x8 __attribute__((ext_vector_type(8)));
typedef _Float16 f16x4 __attribute__((ext_vector_type(4)));
typedef float    f32x4 __attribute__((ext_vector_type(4)));

#define MFMA16(a, b, c) __builtin_amdgcn_mfma_f32_16x16x32_f16((a), (b), (c), 0, 0, 0)
#define GLD_LDS16(gp, lp) \
  __builtin_amdgcn_global_load_lds((const __attribute__((address_space(1))) unsigned int*)(gp), \
                                   (__attribute__((address_space(3))) unsigned int*)(lp), 16, 0, 0)

// ---------- cast fp32 -> fp16, 8 elements/thread ----------
__global__ __launch_bounds__(256) void cast_f16(const float* __restrict__ in,
                                                _Float16* __restrict__ out, int n8) {
  int i = blockIdx.x * 256 + threadIdx.x;
  if (i >= n8) return;
  float4 a = ((const float4*)in)[i * 2];
  float4 b = ((const float4*)in)[i * 2 + 1];
  f16x8 o;
  o[0] = (_Float16)a.x; o[1] = (_Float16)a.y; o[2] = (_Float16)a.z; o[3] = (_Float16)a.w;
  o[4] = (_Float16)b.x; o[5] = (_Float16)b.y; o[6] = (_Float16)b.z; o[7] = (_Float16)b.w;
  ((f16x8*)out)[i] = o;
}

// ---------- W[K][N] fp32 -> WT[N][K] fp16 (64x64 tiles) ----------
__global__ __launch_bounds__(256) void transpose_cast(const float* __restrict__ W,
                                                      _Float16* __restrict__ WT,
                                                      int K, int N) {
  __shared__ _Float16 T[64 * 72];  // T[col_local][row_local], pitch 72
  const int tid = threadIdx.x;
  const int r0 = blockIdx.y * 64, c0 = blockIdx.x * 64;
#pragma unroll
  for (int it = 0; it < 4; ++it) {
    const int row = it * 16 + (tid >> 4);
    const int col4 = (tid & 15) * 4;
    float4 wv = *(const float4*)(W + (size_t)(r0 + row) * N + c0 + col4);
    T[(col4 + 0) * 72 + row] = (_Float16)wv.x;
    T[(col4 + 1) * 72 + row] = (_Float16)wv.y;
    T[(col4 + 2) * 72 + row] = (_Float16)wv.z;
    T[(col4 + 3) * 72 + row] = (_Float16)wv.w;
  }
  __syncthreads();
#pragma unroll
  for (int it = 0; it < 2; ++it) {
    const int g = it * 256 + tid;
    const int col = g >> 3, seg = g & 7;
    *(f16x8*)(WT + (size_t)(c0 + col) * K + r0 + seg * 8) = *(const f16x8*)(T + col * 72 + seg * 8);
  }
}

// ---------- pack mask int32 -> bit per element (64-bit words along k) ----------
__global__ __launch_bounds__(256) void pack_mask(const int* __restrict__ mask,
                                                 unsigned long long* __restrict__ mb) {
  const size_t i = (size_t)blockIdx.x * 256 + threadIdx.x;
  const int m = mask[i];
  unsigned long long bits = __ballot(m != 0);
  if ((threadIdx.x & 63) == 0) mb[i >> 6] = bits;
}

// ---------- GEMM: C[M][N] = A[M][K] * BT[N][K]^T + bias, fp16 MFMA ----------
// 128x128 tile, BK=32, 256 threads (2x2 waves of 64x64), global_load_lds width-16.
template <typename OutT>
__global__ __launch_bounds__(256) void gemm_bt(const _Float16* __restrict__ A,
                                               const _Float16* __restrict__ BT,
                                               const float* __restrict__ bias,
                                               OutT* __restrict__ C,
                                               int M, int N, int K) {
  __shared__ _Float16 As[128 * 32];
  __shared__ _Float16 Bs[128 * 32];
  const int tid = threadIdx.x;
  const int l15 = tid & 15;
  const int quad = (tid & 63) >> 4;
  const int w = tid >> 6;
  const int wm = w >> 1, wn = w & 1;
  const int rowbase = blockIdx.y * 128;
  const int colbase = blockIdx.x * 128;

  f32x4 acc[4][4] = {};

  const int g0 = tid, g1 = 256 + tid;
  const _Float16* Ag0 = A + (size_t)(rowbase + (g0 >> 2)) * K + (g0 & 3) * 8;
  const _Float16* Ag1 = A + (size_t)(rowbase + (g1 >> 2)) * K + (g1 & 3) * 8;
  const _Float16* Bg0 = BT + (size_t)(colbase + (g0 >> 2)) * K + (g0 & 3) * 8;
  const _Float16* Bg1 = BT + (size_t)(colbase + (g1 >> 2)) * K + (g1 & 3) * 8;

  for (int k0 = 0; k0 < K; k0 += 32) {
    __syncthreads();
    GLD_LDS16(Ag0 + k0, As + g0 * 8);
    GLD_LDS16(Ag1 + k0, As + g1 * 8);
    GLD_LDS16(Bg0 + k0, Bs + g0 * 8);
    GLD_LDS16(Bg1 + k0, Bs + g1 * 8);
    __syncthreads();
    f16x8 a[4], b[4];
#pragma unroll
    for (int mt = 0; mt < 4; ++mt)
      a[mt] = *(const f16x8*)(As + (wm * 64 + mt * 16 + l15) * 32 + quad * 8);
#pragma unroll
    for (int nt = 0; nt < 4; ++nt)
      b[nt] = *(const f16x8*)(Bs + (wn * 64 + nt * 16 + l15) * 32 + quad * 8);
#pragma unroll
    for (int mt = 0; mt < 4; ++mt)
#pragma unroll
      for (int nt = 0; nt < 4; ++nt)
        acc[mt][nt] = MFMA16(a[mt], b[nt], acc[mt][nt]);
  }

  float bv[4];
#pragma unroll
  for (int nt = 0; nt < 4; ++nt) bv[nt] = bias[colbase + wn * 64 + nt * 16 + l15];
#pragma unroll
  for (int mt = 0; mt < 4; ++mt)
#pragma unroll
    for (int nt = 0; nt < 4; ++nt) {
      const int col = colbase + wn * 64 + nt * 16 + l15;
#pragma unroll
      for (int r = 0; r < 4; ++r) {
        const int row = rowbase + wm * 64 + mt * 16 + quad * 4 + r;
        C[(size_t)row * N + col] = (OutT)(acc[mt][nt][r] + bv[nt]);
      }
    }
}

// ---------- MFMA flash attention ----------
// qkv16 [B,S,3072] fp16, head h at col h*192 (+0 q, +64 k, +128 v).
// Block = (b,h,q-tile of 64). Wave w owns q rows w*16..w*16+15 and all 64 k-cols
// -> softmax reduce is intra-wave (16-lane shfl). V transposed during staging.
#define AP 72  // LDS pitch (fp16): 2-way bank aliasing only (free)
__global__ __launch_bounds__(256) void attn(const _Float16* __restrict__ qkv,
                                            const unsigned long long* __restrict__ mb,
                                            _Float16* __restrict__ vals) {
  __shared__ _Float16 Qs[64 * AP];
  __shared__ _Float16 Ks[64 * AP];
  __shared__ _Float16 Vt[64 * AP];       // Vt[d][sk]
  __shared__ _Float16 Ps[4][16 * AP];    // per-wave P
  const int tid = threadIdx.x;
  const int l15 = tid & 15;
  const int quad = (tid & 63) >> 4;
  const int w = tid >> 6;
  const int b = blockIdx.y >> 4, h = blockIdx.y & 15;
  const int q0 = blockIdx.x << 6;
  const _Float16* hb = qkv + (size_t)b * SEQ * D3 + h * (3 * HD);

  // stage Q (once)
#pragma unroll
  for (int it = 0; it < 2; ++it) {
    const int g = it * 256 + tid;
    const int row = g >> 3, seg = g & 7;
    *(f16x8*)(Qs + row * AP + seg * 8) = *(const f16x8*)(hb + (size_t)(q0 + row) * D3 + seg * 8);
  }

  float m_[4], l_[4];
  f32x4 o_[4] = {};
#pragma unroll
  for (int r = 0; r < 4; ++r) { m_[r] = -1e30f; l_[r] = 0.f; }

  for (int kt = 0; kt < 16; ++kt) {
    const int k0 = kt << 6;
    __syncthreads();  // prev iter done reading Ks/Vt
    // stage K
#pragma unroll
    for (int it = 0; it < 2; ++it) {
      const int g = it * 256 + tid;
      const int row = g >> 3, seg = g & 7;
      *(f16x8*)(Ks + row * AP + seg * 8) =
          *(const f16x8*)(hb + (size_t)(k0 + row) * D3 + HD + seg * 8);
    }
    // stage V transposed: Vt[d][s]
    {
      const int s = tid >> 2, dseg = tid & 3;
      const _Float16* vp = hb + (size_t)(k0 + s) * D3 + 2 * HD + dseg * 16;
      f16x8 v0 = *(const f16x8*)(vp);
      f16x8 v1 = *(const f16x8*)(vp + 8);
#pragma unroll
      for (int j = 0; j < 8; ++j) Vt[(dseg * 16 + j) * AP + s] = v0[j];
#pragma unroll
      for (int j = 0; j < 8; ++j) Vt[(dseg * 16 + 8 + j) * AP + s] = v1[j];
    }
    __syncthreads();

    // S = Q K^T  (wave w: m-tile = w, n-tiles 0..3)
    f16x8 qa0 = *(const f16x8*)(Qs + (w * 16 + l15) * AP + quad * 8);
    f16x8 qa1 = *(const f16x8*)(Qs + (w * 16 + l15) * AP + 32 + quad * 8);
    f32x4 s4[4] = {};
#pragma unroll
    for (int nt = 0; nt < 4; ++nt) {
      f16x8 kb0 = *(const f16x8*)(Ks + (nt * 16 + l15) * AP + quad * 8);
      f16x8 kb1 = *(const f16x8*)(Ks + (nt * 16 + l15) * AP + 32 + quad * 8);
      s4[nt] = MFMA16(qa0, kb0, s4[nt]);
      s4[nt] = MFMA16(qa1, kb1, s4[nt]);
    }

    // mask + online softmax (rows quad*4+r of wave's 16-row group)
    unsigned long long mrow[4];
#pragma unroll
    for (int r = 0; r < 4; ++r)
      mrow[r] = mb[((size_t)b * SEQ + q0 + w * 16 + quad * 4 + r) * 16 + kt];
#pragma unroll
    for (int r = 0; r < 4; ++r) {
      float sv[4];
#pragma unroll
      for (int nt = 0; nt < 4; ++nt) {
        sv[nt] = s4[nt][r] * 0.125f;
        if (!((mrow[r] >> (nt * 16 + l15)) & 1ull)) sv[nt] = -1e20f;
      }
      float rmax = fmaxf(fmaxf(sv[0], sv[1]), fmaxf(sv[2], sv[3]));
      rmax = fmaxf(rmax, __shfl_xor(rmax, 1));
      rmax = fmaxf(rmax, __shfl_xor(rmax, 2));
      rmax = fmaxf(rmax, __shfl_xor(rmax, 4));
      rmax = fmaxf(rmax, __shfl_xor(rmax, 8));
      const float mnew = fmaxf(m_[r], rmax);
      const float alpha = __expf(m_[r] - mnew);
      float p[4], rsum = 0.f;
#pragma unroll
      for (int nt = 0; nt < 4; ++nt) { p[nt] = __expf(sv[nt] - mnew); rsum += p[nt]; }
      rsum += __shfl_xor(rsum, 1);
      rsum += __shfl_xor(rsum, 2);
      rsum += __shfl_xor(rsum, 4);
      rsum += __shfl_xor(rsum, 8);
      l_[r] = l_[r] * alpha + rsum;
      m_[r] = mnew;
#pragma unroll
      for (int dt = 0; dt < 4; ++dt) o_[dt][r] *= alpha;
#pragma unroll
      for (int nt = 0; nt < 4; ++nt)
        Ps[w][(quad * 4 + r) * AP + nt * 16 + l15] = (_Float16)p[nt];
    }
    // P V  (wave-private P, no barrier needed; compiler inserts lgkmcnt waits)
    f16x8 pa0 = *(const f16x8*)(&Ps[w][l15 * AP + quad * 8]);
    f16x8 pa1 = *(const f16x8*)(&Ps[w][l15 * AP + 32 + quad * 8]);
#pragma unroll
    for (int dt = 0; dt < 4; ++dt) {
      f16x8 vb0 = *(const f16x8*)(Vt + (dt * 16 + l15) * AP + quad * 8);
      f16x8 vb1 = *(const f16x8*)(Vt + (dt * 16 + l15) * AP + 32 + quad * 8);
      o_[dt] = MFMA16(pa0, vb0, o_[dt]);
      o_[dt] = MFMA16(pa1, vb1, o_[dt]);
    }
  }

  // normalize + write vals16[b, q, h*64+d]
#pragma unroll
  for (int r = 0; r < 4; ++r) {
    const float inv = 1.0f / l_[r];
    const int row = q0 + w * 16 + quad * 4 + r;
#pragma unroll
    for (int dt = 0; dt < 4; ++dt) {
      const int col = h * HD + dt * 16 + l15;
      vals[(size_t)(b * SEQ + row) * DM + col] = (_Float16)(o_[dt][r] * inv);
    }
  }
}

extern "C" void kernel_launch(void* const* d_in, const int* in_sizes, int n_in,
                              void* d_out, int out_size, void* d_ws, size_t ws_size,
                              hipStream_t stream) {
  const float* x    = (const float*)d_in[0];
  const int*   mask = (const int*)  d_in[1];
  const float* Wqkv = (const float*)d_in[2];
  const float* bqkv = (const float*)d_in[3];
  const float* Wo   = (const float*)d_in[4];
  const float* bo   = (const float*)d_in[5];
  float* out = (float*)d_out;

  char* ws = (char*)d_ws;
  _Float16* qkv16  = (_Float16*)ws;                       ws += (size_t)BATCH*SEQ*D3*2;   // 24MB
  _Float16* x16    = (_Float16*)ws;                       ws += (size_t)BATCH*SEQ*DM*2;   //  8MB
  _Float16* WqkvT  = (_Float16*)ws;                       ws += (size_t)DM*D3*2;          //  6MB
  _Float16* WoT    = (_Float16*)ws;                       ws += (size_t)DM*DM*2;          //  2MB
  _Float16* vals16 = (_Float16*)ws;                       ws += (size_t)BATCH*SEQ*DM*2;   //  8MB
  unsigned long long* mbits = (unsigned long long*)ws;    // 0.5MB

  cast_f16<<<(BATCH*SEQ*DM/8 + 255)/256, 256, 0, stream>>>(x, x16, BATCH*SEQ*DM/8);
  transpose_cast<<<dim3(D3/64, DM/64), 256, 0, stream>>>(Wqkv, WqkvT, DM, D3);
  transpose_cast<<<dim3(DM/64, DM/64), 256, 0, stream>>>(Wo, WoT, DM, DM);
  pack_mask<<<(BATCH*SEQ*SEQ)/256, 256, 0, stream>>>(mask, mbits);

  gemm_bt<_Float16><<<dim3(D3/128, BATCH*SEQ/128), 256, 0, stream>>>(
      x16, WqkvT, bqkv, qkv16, BATCH*SEQ, D3, DM);
  attn<<<dim3(SEQ/64, BATCH*NH), 256, 0, stream>>>(qkv16, mbits, vals16);
  gemm_bt<float><<<dim3(DM/128, BATCH*SEQ/128), 256, 0, stream>>>(
      vals16, WoT, bo, out, BATCH*SEQ, DM, DM);
}

// Round 3
// 226.576 us; speedup vs baseline: 4.0092x; 1.1029x over previous
//
#include <hip/hip_runtime.h>
#include <cstddef>
#include <cstdint>

#define BATCH 4
#define SEQ   1024
#define DM    1024
#define NH    16
#define HD    64
#define D3    3072
#define LOG2E 1.44269504088896340736f

typedef _Float16 f16x8 __attribute__((ext_vector_type(8)));
typedef _Float16 f16x4 __attribute__((ext_vector_type(4)));
typedef float    f32x4 __attribute__((ext_vector_type(4)));

#define MFMA16(a, b, c) __builtin_amdgcn_mfma_f32_16x16x32_f16((a), (b), (c), 0, 0, 0)
#define GLD_LDS16(gp, lp) \
  __builtin_amdgcn_global_load_lds((const __attribute__((address_space(1))) unsigned int*)(gp), \
                                   (__attribute__((address_space(3))) unsigned int*)(lp), 16, 0, 0)

// ---------- cast fp32 -> fp16 ----------
__global__ __launch_bounds__(256) void cast_f16(const float* __restrict__ in,
                                                _Float16* __restrict__ out, int n8) {
  int i = blockIdx.x * 256 + threadIdx.x;
  if (i >= n8) return;
  float4 a = ((const float4*)in)[i * 2];
  float4 b = ((const float4*)in)[i * 2 + 1];
  f16x8 o;
  o[0] = (_Float16)a.x; o[1] = (_Float16)a.y; o[2] = (_Float16)a.z; o[3] = (_Float16)a.w;
  o[4] = (_Float16)b.x; o[5] = (_Float16)b.y; o[6] = (_Float16)b.z; o[7] = (_Float16)b.w;
  ((f16x8*)out)[i] = o;
}

// ---------- W[K][N] fp32 -> WT[N][K] fp16 ----------
__global__ __launch_bounds__(256) void transpose_cast(const float* __restrict__ W,
                                                      _Float16* __restrict__ WT,
                                                      int K, int N) {
  __shared__ _Float16 T[64 * 72];
  const int tid = threadIdx.x;
  const int r0 = blockIdx.y * 64, c0 = blockIdx.x * 64;
#pragma unroll
  for (int it = 0; it < 4; ++it) {
    const int row = it * 16 + (tid >> 4);
    const int col4 = (tid & 15) * 4;
    float4 wv = *(const float4*)(W + (size_t)(r0 + row) * N + c0 + col4);
    T[(col4 + 0) * 72 + row] = (_Float16)wv.x;
    T[(col4 + 1) * 72 + row] = (_Float16)wv.y;
    T[(col4 + 2) * 72 + row] = (_Float16)wv.z;
    T[(col4 + 3) * 72 + row] = (_Float16)wv.w;
  }
  __syncthreads();
#pragma unroll
  for (int it = 0; it < 2; ++it) {
    const int g = it * 256 + tid;
    const int col = g >> 3, seg = g & 7;
    *(f16x8*)(WT + (size_t)(c0 + col) * K + r0 + seg * 8) = *(const f16x8*)(T + col * 72 + seg * 8);
  }
}

// ---------- pack mask -> bit per element ----------
__global__ __launch_bounds__(256) void pack_mask(const int* __restrict__ mask,
                                                 unsigned long long* __restrict__ mb) {
  const size_t i = (size_t)blockIdx.x * 256 + threadIdx.x;
  const int m = mask[i];
  unsigned long long bits = __ballot(m != 0);
  if ((threadIdx.x & 63) == 0) mb[i >> 6] = bits;
}

// ---------- GEMM: C = A * BT^T + bias. QKV variant: q-cols scaled 1/8,
// v-cols redirected to vT[b,h,d,s] (f16x4 packed), k-cols normal. ----------
template <typename OutT, bool QKV>
__global__ __launch_bounds__(256) void gemm_bt(const _Float16* __restrict__ A,
                                               const _Float16* __restrict__ BT,
                                               const float* __restrict__ bias,
                                               OutT* __restrict__ C,
                                               _Float16* __restrict__ vTp,
                                               int M, int N, int K) {
  __shared__ _Float16 As[128 * 32];
  __shared__ _Float16 Bs[128 * 32];
  const int tid = threadIdx.x;
  const int l15 = tid & 15;
  const int quad = (tid & 63) >> 4;
  const int w = tid >> 6;
  const int wm = w >> 1, wn = w & 1;
  const int rowbase = blockIdx.y * 128;
  const int colbase = blockIdx.x * 128;

  f32x4 acc[4][4] = {};
  const int g0 = tid, g1 = 256 + tid;
  const _Float16* Ag0 = A + (size_t)(rowbase + (g0 >> 2)) * K + (g0 & 3) * 8;
  const _Float16* Ag1 = A + (size_t)(rowbase + (g1 >> 2)) * K + (g1 & 3) * 8;
  const _Float16* Bg0 = BT + (size_t)(colbase + (g0 >> 2)) * K + (g0 & 3) * 8;
  const _Float16* Bg1 = BT + (size_t)(colbase + (g1 >> 2)) * K + (g1 & 3) * 8;

  for (int k0 = 0; k0 < K; k0 += 32) {
    __syncthreads();
    GLD_LDS16(Ag0 + k0, As + g0 * 8);
    GLD_LDS16(Ag1 + k0, As + g1 * 8);
    GLD_LDS16(Bg0 + k0, Bs + g0 * 8);
    GLD_LDS16(Bg1 + k0, Bs + g1 * 8);
    __syncthreads();
    f16x8 a[4], b[4];
#pragma unroll
    for (int mt = 0; mt < 4; ++mt)
      a[mt] = *(const f16x8*)(As + (wm * 64 + mt * 16 + l15) * 32 + quad * 8);
#pragma unroll
    for (int nt = 0; nt < 4; ++nt)
      b[nt] = *(const f16x8*)(Bs + (wn * 64 + nt * 16 + l15) * 32 + quad * 8);
#pragma unroll
    for (int mt = 0; mt < 4; ++mt)
#pragma unroll
      for (int nt = 0; nt < 4; ++nt)
        acc[mt][nt] = MFMA16(a[mt], b[nt], acc[mt][nt]);
  }

  float bv[4];
#pragma unroll
  for (int nt = 0; nt < 4; ++nt) bv[nt] = bias[colbase + wn * 64 + nt * 16 + l15];
#pragma unroll
  for (int mt = 0; mt < 4; ++mt)
#pragma unroll
    for (int nt = 0; nt < 4; ++nt) {
      const int col = colbase + wn * 64 + nt * 16 + l15;
      if (QKV) {
        const int reg3 = (col >> 6) % 3;  // wave-uniform: 16-col group inside one 64-block
        if (reg3 == 2) {
          const int hh = col / 192;
          const int d = col - hh * 192 - 128;
          const int row0 = rowbase + wm * 64 + mt * 16 + quad * 4;
          const int bb = row0 >> 10, s0 = row0 & 1023;
          f16x4 pk;
#pragma unroll
          for (int r = 0; r < 4; ++r) pk[r] = (_Float16)(acc[mt][nt][r] + bv[nt]);
          *(f16x4*)(vTp + ((size_t)((bb * NH + hh) * HD + d)) * SEQ + s0) = pk;
        } else {
          const float sc = (reg3 == 0) ? 0.125f : 1.f;  // fold 1/sqrt(hd) into Q
#pragma unroll
          for (int r = 0; r < 4; ++r) {
            const int row = rowbase + wm * 64 + mt * 16 + quad * 4 + r;
            C[(size_t)row * N + col] = (OutT)((acc[mt][nt][r] + bv[nt]) * sc);
          }
        }
      } else {
#pragma unroll
        for (int r = 0; r < 4; ++r) {
          const int row = rowbase + wm * 64 + mt * 16 + quad * 4 + r;
          C[(size_t)row * N + col] = (OutT)(acc[mt][nt][r] + bv[nt]);
        }
      }
    }
}

// ---------- MFMA flash attention, transposed-S scheme ----------
// S^T = K Q^T -> lane owns one q (col=l15), 16 k in regs -> 2-shfl softmax.
// P packs to f16x4 ds_write_b64; PV uses vT tiles staged conflict-free.
// K/V/mask for tile kt+1 prefetched into VGPRs during tile kt compute.
__global__ __launch_bounds__(256) void attn(const _Float16* __restrict__ qkv,
                                            const _Float16* __restrict__ vT,
                                            const unsigned long long* __restrict__ mb,
                                            _Float16* __restrict__ vals) {
  __shared__ _Float16 Ks[64 * 72];
  __shared__ _Float16 Vt[64 * 72];
  __shared__ _Float16 Ps[4][16 * 72];
  const int tid = threadIdx.x;
  const int l15 = tid & 15, quad = (tid & 63) >> 4, w = tid >> 6;
  const int b = blockIdx.y >> 4, h = blockIdx.y & 15;
  const int q0 = blockIdx.x << 6;

  // Q fragments straight from global (pre-scaled by 1/8 in GEMM epilogue)
  const _Float16* qrow = qkv + (size_t)(b * SEQ + q0 + w * 16 + l15) * D3 + h * 192;
  const f16x8 qa0 = *(const f16x8*)(qrow + quad * 8);
  const f16x8 qa1 = *(const f16x8*)(qrow + 32 + quad * 8);

  const int sr = tid >> 3, sseg = tid & 7;  // K staging: rows sr, sr+32
  const _Float16* kbase = qkv + (size_t)b * SEQ * D3 + h * 192 + 64;
  const int vd = tid >> 2, vs = tid & 3;    // V staging: row d=vd, segs vs, vs+4
  const _Float16* vbase = vT + (size_t)((b * NH + h) * HD + vd) * SEQ;
  const size_t mbase = (size_t)(b * SEQ + q0 + w * 16 + l15) * 16;

  f16x8 k0r = *(const f16x8*)(kbase + (size_t)sr * D3 + sseg * 8);
  f16x8 k1r = *(const f16x8*)(kbase + (size_t)(32 + sr) * D3 + sseg * 8);
  f16x8 v0r = *(const f16x8*)(vbase + vs * 8);
  f16x8 v1r = *(const f16x8*)(vbase + 32 + vs * 8);
  unsigned long long mrow = mb[mbase];

  float m_ = -1e30f, l_ = 0.f;
  f32x4 o_[4] = {};

  for (int kt = 0; kt < 16; ++kt) {
    if (kt) __syncthreads();
    *(f16x8*)(Ks + sr * 72 + sseg * 8) = k0r;
    *(f16x8*)(Ks + (sr + 32) * 72 + sseg * 8) = k1r;
    *(f16x8*)(Vt + vd * 72 + vs * 8) = v0r;
    *(f16x8*)(Vt + vd * 72 + 32 + vs * 8) = v1r;
    __syncthreads();
    const unsigned long long mcur = mrow;
    if (kt < 15) {  // prefetch next tile; vmcnt drains at next barrier
      const int kn = (kt + 1) << 6;
      k0r = *(const f16x8*)(kbase + (size_t)(kn + sr) * D3 + sseg * 8);
      k1r = *(const f16x8*)(kbase + (size_t)(kn + 32 + sr) * D3 + sseg * 8);
      v0r = *(const f16x8*)(vbase + kn + vs * 8);
      v1r = *(const f16x8*)(vbase + kn + 32 + vs * 8);
      mrow = mb[mbase + kt + 1];
    }
    // S^T = K Q^T : col=l15=q, row=quad*4+r (+16*mt) = k
    f32x4 st[4] = {};
#pragma unroll
    for (int mt = 0; mt < 4; ++mt) {
      f16x8 ka0 = *(const f16x8*)(Ks + (mt * 16 + l15) * 72 + quad * 8);
      f16x8 ka1 = *(const f16x8*)(Ks + (mt * 16 + l15) * 72 + 32 + quad * 8);
      st[mt] = MFMA16(ka0, qa0, st[mt]);
      st[mt] = MFMA16(ka1, qa1, st[mt]);
    }
    // softmax in log2 domain; max over unmasked superset (shift-invariant)
    float tv[16];
#pragma unroll
    for (int mt = 0; mt < 4; ++mt)
#pragma unroll
      for (int r = 0; r < 4; ++r) tv[mt * 4 + r] = st[mt][r] * LOG2E;
    float tmax = tv[0];
#pragma unroll
    for (int i = 1; i < 16; ++i) tmax = fmaxf(tmax, tv[i]);
    tmax = fmaxf(tmax, __shfl_xor(tmax, 16));
    tmax = fmaxf(tmax, __shfl_xor(tmax, 32));
    const float mnew = fmaxf(m_, tmax);
    const float alpha = exp2f(m_ - mnew);
    const unsigned int wlo = (unsigned int)(mcur >> (quad * 4));
    const unsigned int whi = (unsigned int)(mcur >> (quad * 4 + 32));
    float rsum = 0.f;
#pragma unroll
    for (int mt = 0; mt < 4; ++mt) {
      const unsigned int wsel = (mt < 2) ? wlo : whi;
      const int shb = (mt & 1) * 16;
#pragma unroll
      for (int r = 0; r < 4; ++r) {
        float e = exp2f(tv[mt * 4 + r] - mnew);
        e = ((wsel >> (shb + r)) & 1u) ? e : 0.f;
        tv[mt * 4 + r] = e;
        rsum += e;
      }
    }
    rsum += __shfl_xor(rsum, 16);
    rsum += __shfl_xor(rsum, 32);
    l_ = l_ * alpha + rsum;
    m_ = mnew;
    // stage P (wave-private, b64 writes)
#pragma unroll
    for (int mt = 0; mt < 4; ++mt) {
      f16x4 pk;
#pragma unroll
      for (int r = 0; r < 4; ++r) pk[r] = (_Float16)tv[mt * 4 + r];
      *(f16x4*)(&Ps[w][l15 * 72 + mt * 16 + quad * 4]) = pk;
    }
    // broadcast alpha to O-layout lanes, rescale
    float aq[4];
#pragma unroll
    for (int r = 0; r < 4; ++r) aq[r] = __shfl(alpha, quad * 4 + r);
#pragma unroll
    for (int nt = 0; nt < 4; ++nt) {
      o_[nt][0] *= aq[0]; o_[nt][1] *= aq[1]; o_[nt][2] *= aq[2]; o_[nt][3] *= aq[3];
    }
    // O += P V : A=P (m=q), B=V via vT rows (n=d)
    f16x8 pa0 = *(const f16x8*)(&Ps[w][l15 * 72 + quad * 8]);
    f16x8 pa1 = *(const f16x8*)(&Ps[w][l15 * 72 + 32 + quad * 8]);
#pragma unroll
    for (int nt = 0; nt < 4; ++nt) {
      f16x8 vb0 = *(const f16x8*)(Vt + (nt * 16 + l15) * 72 + quad * 8);
      f16x8 vb1 = *(const f16x8*)(Vt + (nt * 16 + l15) * 72 + 32 + quad * 8);
      o_[nt] = MFMA16(pa0, vb0, o_[nt]);
      o_[nt] = MFMA16(pa1, vb1, o_[nt]);
    }
  }
  const float inv = 1.f / l_;
  float iq[4];
#pragma unroll
  for (int r = 0; r < 4; ++r) iq[r] = __shfl(inv, quad * 4 + r);
#pragma unroll
  for (int nt = 0; nt < 4; ++nt)
#pragma unroll
    for (int r = 0; r < 4; ++r)
      vals[(size_t)(b * SEQ + q0 + w * 16 + quad * 4 + r) * DM + h * HD + nt * 16 + l15] =
          (_Float16)(o_[nt][r] * iq[r]);
}

extern "C" void kernel_launch(void* const* d_in, const int* in_sizes, int n_in,
                              void* d_out, int out_size, void* d_ws, size_t ws_size,
                              hipStream_t stream) {
  const float* x    = (const float*)d_in[0];
  const int*   mask = (const int*)  d_in[1];
  const float* Wqkv = (const float*)d_in[2];
  const float* bqkv = (const float*)d_in[3];
  const float* Wo   = (const float*)d_in[4];
  const float* bo   = (const float*)d_in[5];
  float* out = (float*)d_out;

  char* ws = (char*)d_ws;
  _Float16* qkv16  = (_Float16*)ws;                    ws += (size_t)BATCH*SEQ*D3*2;   // 24MB (v-cols unused)
  _Float16* vT16   = (_Float16*)ws;                    ws += (size_t)BATCH*DM*SEQ*2;   //  8MB
  _Float16* x16    = (_Float16*)ws;                    ws += (size_t)BATCH*SEQ*DM*2;   //  8MB
  _Float16* WqkvT  = (_Float16*)ws;                    ws += (size_t)DM*D3*2;          //  6MB
  _Float16* WoT    = (_Float16*)ws;                    ws += (size_t)DM*DM*2;          //  2MB
  _Float16* vals16 = (_Float16*)ws;                    ws += (size_t)BATCH*SEQ*DM*2;   //  8MB
  unsigned long long* mbits = (unsigned long long*)ws;                                 // 0.5MB

  cast_f16<<<(BATCH*SEQ*DM/8 + 255)/256, 256, 0, stream>>>(x, x16, BATCH*SEQ*DM/8);
  transpose_cast<<<dim3(D3/64, DM/64), 256, 0, stream>>>(Wqkv, WqkvT, DM, D3);
  transpose_cast<<<dim3(DM/64, DM/64), 256, 0, stream>>>(Wo, WoT, DM, DM);
  pack_mask<<<(BATCH*SEQ*SEQ)/256, 256, 0, stream>>>(mask, mbits);

  gemm_bt<_Float16, true><<<dim3(D3/128, BATCH*SEQ/128), 256, 0, stream>>>(
      x16, WqkvT, bqkv, qkv16, vT16, BATCH*SEQ, D3, DM);
  attn<<<dim3(SEQ/64, BATCH*NH), 256, 0, stream>>>(qkv16, vT16, mbits, vals16);
  gemm_bt<float, false><<<dim3(DM/128, BATCH*SEQ/128), 256, 0, stream>>>(
      vals16, WoT, bo, out, nullptr, BATCH*SEQ, DM, DM);
}